// Round 16
// baseline (1374.837 us; speedup 1.0000x reference)
//
#include <hip/hip_runtime.h>

#define NEGV (-10000.0f)

static constexpr int Bb    = 128;
static constexpr int Tt    = 512;
static constexpr int Mrows = Bb * Tt;   // 65536
static constexpr int Hh    = 50;
static constexpr int START = 5;

typedef __attribute__((ext_vector_type(8))) short bf16x8;
typedef __attribute__((ext_vector_type(4))) float f32x4;
typedef __attribute__((ext_vector_type(2))) _Float16 h2t;

__device__ __forceinline__ float fsig(float x) {
    return __builtin_amdgcn_rcpf(1.0f + __expf(-x));
}
__device__ __forceinline__ float ftanh(float x) {
    return 2.0f * __builtin_amdgcn_rcpf(1.0f + __expf(-2.0f * x)) - 1.0f;
}
__device__ __forceinline__ unsigned short f2bf(float f) {
    unsigned u = __float_as_uint(f);
    u = (u + 0x7fffu + ((u >> 16) & 1u)) >> 16;   // RNE
    return (unsigned short)u;
}
#define BF(u) __uint_as_float(((unsigned)(u)) << 16)

// ---------------------------------------------------------------------------
// Convert W [400][K] fp32 -> [448][KP] bf16 (zero-padded rows/cols)
// ---------------------------------------------------------------------------
__global__ __launch_bounds__(256) void conv_w(
    const float* __restrict__ src, unsigned short* __restrict__ dst,
    int K, int KP)
{
    int gid = blockIdx.x * 256 + threadIdx.x;
    int tot = 448 * KP;
    if (gid >= tot) return;
    int r = gid / KP, c = gid % KP;
    float v = (r < 400 && c < K) ? src[r * K + c] : 0.f;
    dst[gid] = f2bf(v);
}

// ---------------------------------------------------------------------------
// Convert A rows (gathered, layer 0 only) fp32 -> [M][KP] bf16
// ---------------------------------------------------------------------------
template <bool GATHER>
__global__ __launch_bounds__(256) void conv_a(
    const float* __restrict__ src, const int* __restrict__ idx,
    unsigned short* __restrict__ dst, int K, int KP, int cpr)
{
    long gid = (long)blockIdx.x * 256 + threadIdx.x;
    long tot = (long)Mrows * cpr;
    if (gid >= tot) return;
    long m = gid / cpr;
    int p = (int)(gid - m * cpr) * 8;
    const float* s = src + (GATHER ? (long)idx[m] : m) * K;
    unsigned u0, u1, u2, u3;
    {
        float x0 = (p + 0 < K) ? s[p + 0] : 0.f;
        float x1 = (p + 1 < K) ? s[p + 1] : 0.f;
        float x2 = (p + 2 < K) ? s[p + 2] : 0.f;
        float x3 = (p + 3 < K) ? s[p + 3] : 0.f;
        float x4 = (p + 4 < K) ? s[p + 4] : 0.f;
        float x5 = (p + 5 < K) ? s[p + 5] : 0.f;
        float x6 = (p + 6 < K) ? s[p + 6] : 0.f;
        float x7 = (p + 7 < K) ? s[p + 7] : 0.f;
        u0 = (unsigned)f2bf(x0) | ((unsigned)f2bf(x1) << 16);
        u1 = (unsigned)f2bf(x2) | ((unsigned)f2bf(x3) << 16);
        u2 = (unsigned)f2bf(x4) | ((unsigned)f2bf(x5) << 16);
        u3 = (unsigned)f2bf(x6) | ((unsigned)f2bf(x7) << 16);
    }
    uint4 v = make_uint4(u0, u1, u2, u3);
    *(uint4*)(dst + m * KP + p) = v;
}

// ---------------------------------------------------------------------------
// bf16 MFMA GEMM: C[M,400]bf16 = A[M,KP]bf16 @ W[448,KP]bf16^T + bias
// (unchanged from r10/r11, verified)
// ---------------------------------------------------------------------------
__global__ __launch_bounds__(256) void gemm_mfma(
    const unsigned short* __restrict__ Ab,   // [M][KP]
    const unsigned short* __restrict__ Wb,   // [448][KP]
    const float* __restrict__ bias,          // [400]
    unsigned short* __restrict__ C,          // [M][400] bf16
    int KP)
{
    __shared__ unsigned short As[128][40];
    __shared__ unsigned short Ws[64][40];

    const int tid = threadIdx.x;
    const int m0 = blockIdx.x * 128;
    const int n0 = blockIdx.y * 64;

    const int w  = tid >> 6, l = tid & 63;
    const int wm = (w >> 1) * 64;
    const int wn = (w & 1) * 32;
    const int lr = l & 15;
    const int lk = (l >> 4) * 8;

    f32x4 acc[4][2] = {};

    for (int k0 = 0; k0 < KP; k0 += 32) {
        __syncthreads();
        {
            int c = tid;
            int r = c >> 2, p = (c & 3) * 8;
            *(bf16x8*)&As[r][p] = *(const bf16x8*)(Ab + (long)(m0 + r) * KP + k0 + p);
            c = tid + 256;
            r = c >> 2; p = (c & 3) * 8;
            *(bf16x8*)&As[r][p] = *(const bf16x8*)(Ab + (long)(m0 + r) * KP + k0 + p);
            r = tid >> 2; p = (tid & 3) * 8;
            *(bf16x8*)&Ws[r][p] = *(const bf16x8*)(Wb + (long)(n0 + r) * KP + k0 + p);
        }
        __syncthreads();

        bf16x8 af0 = *(const bf16x8*)&As[wm +  0 + lr][lk];
        bf16x8 af1 = *(const bf16x8*)&As[wm + 16 + lr][lk];
        bf16x8 af2 = *(const bf16x8*)&As[wm + 32 + lr][lk];
        bf16x8 af3 = *(const bf16x8*)&As[wm + 48 + lr][lk];
        bf16x8 wf0 = *(const bf16x8*)&Ws[wn +  0 + lr][lk];
        bf16x8 wf1 = *(const bf16x8*)&Ws[wn + 16 + lr][lk];

        acc[0][0] = __builtin_amdgcn_mfma_f32_16x16x32_bf16(af0, wf0, acc[0][0], 0, 0, 0);
        acc[0][1] = __builtin_amdgcn_mfma_f32_16x16x32_bf16(af0, wf1, acc[0][1], 0, 0, 0);
        acc[1][0] = __builtin_amdgcn_mfma_f32_16x16x32_bf16(af1, wf0, acc[1][0], 0, 0, 0);
        acc[1][1] = __builtin_amdgcn_mfma_f32_16x16x32_bf16(af1, wf1, acc[1][1], 0, 0, 0);
        acc[2][0] = __builtin_amdgcn_mfma_f32_16x16x32_bf16(af2, wf0, acc[2][0], 0, 0, 0);
        acc[2][1] = __builtin_amdgcn_mfma_f32_16x16x32_bf16(af2, wf1, acc[2][1], 0, 0, 0);
        acc[3][0] = __builtin_amdgcn_mfma_f32_16x16x32_bf16(af3, wf0, acc[3][0], 0, 0, 0);
        acc[3][1] = __builtin_amdgcn_mfma_f32_16x16x32_bf16(af3, wf1, acc[3][1], 0, 0, 0);
    }

    const int orow = (l >> 4) * 4;
    const int ocol = l & 15;
    #pragma unroll
    for (int a = 0; a < 4; ++a) {
        #pragma unroll
        for (int bb = 0; bb < 2; ++bb) {
            const int col = n0 + wn + bb * 16 + ocol;
            if (col < 400) {
                const float bv = bias[col];
                #pragma unroll
                for (int i = 0; i < 4; ++i) {
                    const long row = m0 + wm + a * 16 + orow + i;
                    C[row * 400 + col] = f2bf(acc[a][bb][i] + bv);
                }
            }
        }
    }
}

// ---------------------------------------------------------------------------
// LSTM scan: r15's proven 4-wave skeleton (gate-major dot phase, pre[2][200]
// double-buffered, one raw s_barrier/step, lgkm-only drain) with fdot2:
// thread t<200 owns gate row t as 25 packed-fp16 pairs -> 25 readlane +
// 25 v_dot2 (halves r15's 100-op dot issue). NO ds_bpermute (r14's NaN
// suspect): after the barrier, lane k<25 computes activations for units
// 2k,2k+1 directly from pre (c for both in registers) and packs h2 locally
// with cvt_pkrtz. Output: one u32 (2xbf16) store per lane from 25 lanes.
// ---------------------------------------------------------------------------
#if __has_builtin(__builtin_amdgcn_fdot2)
#define DOT2(W, HH, A) A = __builtin_amdgcn_fdot2(W, HH, A, false)
#else
#define DOT2(W, HH, A) A += (float)(W).x * (float)(HH).x + (float)(W).y * (float)(HH).y
#endif

#define LDW(P, Q) __builtin_bit_cast(unsigned, (h2t){(_Float16)(P)[2*(Q)], (_Float16)(P)[2*(Q)+1]})
#define PKH(A, B) __builtin_bit_cast(h2t, __builtin_amdgcn_cvt_pkrtz((A), (B)))
#define LA10(x0,x1,x2,x3,x4,x5,x6,x7,x8,x9) \
    asm volatile("" : "+v"(x0), "+v"(x1), "+v"(x2), "+v"(x3), "+v"(x4), \
                      "+v"(x5), "+v"(x6), "+v"(x7), "+v"(x8), "+v"(x9))
#define LA5(x0,x1,x2,x3,x4) \
    asm volatile("" : "+v"(x0), "+v"(x1), "+v"(x2), "+v"(x3), "+v"(x4))

__global__ void
__attribute__((amdgpu_flat_work_group_size(256, 256), amdgpu_waves_per_eu(1, 1)))
lstm_scan(
    const unsigned short* __restrict__ xg,  // [M,400] bf16 (bias added)
    const float* __restrict__ w_hh,         // [2,200,50]
    const float* __restrict__ h0,           // layer base: [2,B,50]
    const float* __restrict__ c0,
    unsigned short* __restrict__ xout)      // [M,128] bf16, cols 100-127 = 0
{
    const int b    = blockIdx.x & 127;
    const int dir  = blockIdx.x >> 7;
    const int tid  = threadIdx.x;
    const int lane = tid & 63;
    const int wv   = tid >> 6;

    __shared__ float pre[2][200];   // double-buffered pre-gates (only LDS)

    const int gr = (tid < 200) ? tid : 199;

    const float* wr = w_hh + ((long)dir * 200 + gr) * 50;
    unsigned W0=LDW(wr,0), W1=LDW(wr,1), W2=LDW(wr,2), W3=LDW(wr,3), W4=LDW(wr,4);
    unsigned W5=LDW(wr,5), W6=LDW(wr,6), W7=LDW(wr,7), W8=LDW(wr,8), W9=LDW(wr,9);
    unsigned W10=LDW(wr,10),W11=LDW(wr,11),W12=LDW(wr,12),W13=LDW(wr,13),W14=LDW(wr,14);
    unsigned W15=LDW(wr,15),W16=LDW(wr,16),W17=LDW(wr,17),W18=LDW(wr,18),W19=LDW(wr,19);
    unsigned W20=LDW(wr,20),W21=LDW(wr,21),W22=LDW(wr,22),W23=LDW(wr,23),W24=LDW(wr,24);
    LA10(W0,W1,W2,W3,W4,W5,W6,W7,W8,W9);
    LA10(W10,W11,W12,W13,W14,W15,W16,W17,W18,W19);
    LA5(W20,W21,W22,W23,W24);

    // lane k<25 of EVERY wave owns units 2k,2k+1 (redundant across waves)
    float c0r = 0.f, c1r = 0.f;
    h2t hpk = (h2t)(_Float16)0;
    if (lane < 25) {
        const float* cb = c0 + ((long)dir * Bb + b) * Hh;
        const float* hb = h0 + ((long)dir * Bb + b) * Hh;
        c0r = cb[2 * lane];
        c1r = cb[2 * lane + 1];
        hpk = PKH(hb[2 * lane], hb[2 * lane + 1]);
    }
    __syncthreads();

    const long rowbase = (long)b * Tt;
    const unsigned short* xbase = xg + rowbase * 400 + dir * 200 + gr;
    // u32 output slot (2 bf16): units -> dir*25+lane; pad -> 50+(lane-25)
    const int ocw = (lane < 25) ? (dir * 25 + lane) : (50 + (lane - 25));
    unsigned* opw = (unsigned*)xout + rowbase * 64 + ocw;

    #define XLD(s)  xbase[(long)(dir ? (Tt - 1 - (s)) : (s)) * 400]
    #define TTOF(s) (dir ? (Tt - 1 - (s)) : (s))

    #define DD(K, ACC) { \
        h2t hh = __builtin_bit_cast(h2t, (unsigned)__builtin_amdgcn_readlane(hpki, K)); \
        DOT2(__builtin_bit_cast(h2t, W##K), hh, ACC); }

    #define STEP(PRE, XIN, TT) do {                                         \
        if (tid < 200) {                                                    \
            float s0 = BF(XIN), s1 = 0.f;                                   \
            const int hpki = (int)__builtin_bit_cast(unsigned, hpk);        \
            DD(0,s0)  DD(1,s1)  DD(2,s0)  DD(3,s1)  DD(4,s0)                \
            DD(5,s1)  DD(6,s0)  DD(7,s1)  DD(8,s0)  DD(9,s1)                \
            DD(10,s0) DD(11,s1) DD(12,s0) DD(13,s1) DD(14,s0)               \
            DD(15,s1) DD(16,s0) DD(17,s1) DD(18,s0) DD(19,s1)               \
            DD(20,s0) DD(21,s1) DD(22,s0) DD(23,s1) DD(24,s0)               \
            (PRE)[tid] = s0 + s1;                                           \
        }                                                                   \
        asm volatile("s_waitcnt lgkmcnt(0)\n\ts_barrier" ::: "memory");     \
        if (lane < 25) {                                                    \
            const float pi0 = (PRE)[2*lane],       pi1 = (PRE)[2*lane + 1];       \
            const float pf0 = (PRE)[50 + 2*lane],  pf1 = (PRE)[50 + 2*lane + 1];  \
            const float pg0 = (PRE)[100 + 2*lane], pg1 = (PRE)[100 + 2*lane + 1]; \
            const float po0 = (PRE)[150 + 2*lane], po1 = (PRE)[150 + 2*lane + 1]; \
            c0r = fsig(pf0) * c0r + fsig(pi0) * ftanh(pg0);                 \
            c1r = fsig(pf1) * c1r + fsig(pi1) * ftanh(pg1);                 \
            const float h0v = fsig(po0) * ftanh(c0r);                       \
            const float h1v = fsig(po1) * ftanh(c1r);                       \
            hpk = PKH(h0v, h1v);                                            \
            if (wv == 0)                                                    \
                opw[(long)(TT) * 64] = (unsigned)f2bf(h0v)                  \
                                     | ((unsigned)f2bf(h1v) << 16);         \
        } else if (wv == 0 && lane < 39) {                                  \
            opw[(long)(TT) * 64] = 0u;                                      \
        }                                                                   \
    } while (0)

    unsigned xc0 = XLD(0), xc1 = XLD(1), xc2 = XLD(2), xc3 = XLD(3);
    unsigned xn0 = 0, xn1 = 0, xn2 = 0, xn3 = 0;

    for (int blk = 0; blk < Tt / 4; ++blk) {
        const int s0i = blk * 4;
        if (blk < Tt / 4 - 1) {
            xn0 = XLD(s0i + 4); xn1 = XLD(s0i + 5);
            xn2 = XLD(s0i + 6); xn3 = XLD(s0i + 7);
        }
        STEP(pre[0], xc0, TTOF(s0i + 0));
        STEP(pre[1], xc1, TTOF(s0i + 1));
        STEP(pre[0], xc2, TTOF(s0i + 2));
        STEP(pre[1], xc3, TTOF(s0i + 3));
        xc0 = xn0; xc1 = xn1; xc2 = xn2; xc3 = xn3;
    }
    #undef STEP
    #undef DD
    #undef XLD
    #undef TTOF
}

// ---------------------------------------------------------------------------
// feats[row, i] = (x_bf16[row,:100] . w_tag[i,:] + b_tag[i]) * mask[row]
// ---------------------------------------------------------------------------
__global__ __launch_bounds__(256) void feats_kernel(
    const unsigned short* __restrict__ x, // [M,128] bf16
    const float* __restrict__ w_tag,      // [7,100]
    const float* __restrict__ b_tag,      // [7]
    const float* __restrict__ mask,       // [M]
    float* __restrict__ feats)            // [M,8]
{
    const int gid = blockIdx.x * 256 + threadIdx.x;
    const int row = gid >> 3;
    const int i   = gid & 7;
    if (row >= Mrows) return;
    if (i == 7) { feats[(long)row * 8 + 7] = 0.f; return; }
    const unsigned* xr = (const unsigned*)(x + (long)row * 128); // 2 bf16/word
    const float* wr = w_tag + i * 100;
    float acc = b_tag[i];
    #pragma unroll
    for (int q = 0; q < 50; ++q) {
        unsigned v = xr[q];
        float2 w2 = *(const float2*)(wr + 2 * q);
        acc += __uint_as_float(v << 16) * w2.x
             + __uint_as_float(v & 0xffff0000u) * w2.y;
    }
    feats[(long)row * 8 + i] = acc * mask[row];
}

// ---------------------------------------------------------------------------
// Viterbi forward. 8 lanes per batch row; backpointers packed [T][B].
// ---------------------------------------------------------------------------
__global__ __launch_bounds__(64) void viterbi_fwd(
    const float* __restrict__ feats,   // [M,8]
    const float* __restrict__ trans,   // [7,7]
    unsigned int* __restrict__ bptrw,  // [T*B]
    float* __restrict__ best_score,    // [B] -> d_out
    int* __restrict__ best_tag)        // [B] -> ws
{
    const int lane = threadIdx.x;
    const int sub  = lane >> 3;
    const int i    = lane & 7;
    const int b    = blockIdx.x * 8 + sub;
    const int base = lane & 56;

    float tr[7];
    #pragma unroll
    for (int j = 0; j < 7; ++j) tr[j] = (i < 7) ? trans[i * 7 + j] : -1e30f;

    float score = (i == START) ? 0.0f : NEGV;
    const long fb = (long)b * Tt;

    float featc = feats[(fb + 0) * 8 + i];
    for (int t = 0; t < Tt; ++t) {
        float featn = (t + 1 < Tt) ? feats[(fb + t + 1) * 8 + i] : 0.f;
        float best = -3.4e38f;
        int bp = 0;
        #pragma unroll
        for (int j = 0; j < 7; ++j) {
            float sj = __shfl(score, base | j, 64);
            float m = sj + tr[j];
            if (m > best) { best = m; bp = j; }
        }
        if (i < 7) score = best + featc;
        unsigned v = (i < 7) ? ((unsigned)bp << (3 * i)) : 0u;
        v |= __shfl_xor(v, 1, 64);
        v |= __shfl_xor(v, 2, 64);
        v |= __shfl_xor(v, 4, 64);
        if (i == 0) bptrw[(long)t * Bb + b] = v;
        featc = featn;
    }

    float bestv = score;
    int bt = 0;
    #pragma unroll
    for (int j = 1; j < 7; ++j) {
        float sj = __shfl(score, base | j, 64);
        if (i == 0 && sj > bestv) { bestv = sj; bt = j; }
    }
    if (i == 0) {
        best_score[b] = bestv;
        best_tag[b]   = bt;
    }
}

// ---------------------------------------------------------------------------
__global__ __launch_bounds__(128) void backtrack(
    const unsigned int* __restrict__ bptrw,
    const int* __restrict__ best_tag,
    float* __restrict__ out_tags)   // d_out + 128, [B,T]
{
    const int b = threadIdx.x;
    if (b >= Bb) return;
    const long fb = (long)b * Tt;
    int tag = best_tag[b];
    out_tags[fb + Tt - 1] = (float)tag;
    #pragma unroll 8
    for (int t = Tt - 1; t >= 1; --t) {
        unsigned w = bptrw[(long)t * Bb + b];
        tag = (w >> (3 * tag)) & 7;
        out_tags[fb + t - 1] = (float)tag;
    }
}

// ---------------------------------------------------------------------------
extern "C" void kernel_launch(void* const* d_in, const int* in_sizes, int n_in,
                              void* d_out, int out_size, void* d_ws, size_t ws_size,
                              hipStream_t stream)
{
    const int*   sent    = (const int*)  d_in[0];
    const float* mask    = (const float*)d_in[1];
    const float* emb     = (const float*)d_in[2];
    const float* h0      = (const float*)d_in[3];
    const float* c0      = (const float*)d_in[4];
    const float* w_ih_l0 = (const float*)d_in[5];
    const float* w_hh_l0 = (const float*)d_in[6];
    const float* b_l0    = (const float*)d_in[7];
    const float* w_ih_l1 = (const float*)d_in[8];
    const float* w_hh_l1 = (const float*)d_in[9];
    const float* b_l1    = (const float*)d_in[10];
    const float* w_ih_l2 = (const float*)d_in[11];
    const float* w_hh_l2 = (const float*)d_in[12];
    const float* b_l2    = (const float*)d_in[13];
    const float* w_tag   = (const float*)d_in[14];
    const float* b_tag   = (const float*)d_in[15];
    const float* trans   = (const float*)d_in[16];

    float* out = (float*)d_out;
    char* ws = (char*)d_ws;

    // workspace layout (bytes)
    unsigned short* xg    = (unsigned short*)(ws);                  // 52,428,800
    unsigned short* xa16  = (unsigned short*)(ws + 52428800L);      // 16,777,216
    unsigned short* xb16  = (unsigned short*)(ws + 69206016L);      // 16,777,216
    unsigned short* AbR   = (unsigned short*)(ws + 85983232L);      // 41,943,040
    float*          feats = (float*)(ws + 127926272L);              //  2,097,152
    unsigned*       bptrw = (unsigned*)(ws + 130023424L);           //    262,144
    unsigned short* Wb0   = (unsigned short*)(ws + 130285568L);     //    286,720
    unsigned short* Wb1   = (unsigned short*)(ws + 130572288L);     //    114,688
    unsigned short* Wb2   = (unsigned short*)(ws + 130686976L);     //    114,688
    int*            btag  = (int*)(ws + 130801664L);                //        512

    dim3 gridG(Mrows / 128, 7);   // 128x64 tiles over [65536, 448]

    // weight conversions (independent)
    conv_w<<<(448 * 320 + 255) / 256, 256, 0, stream>>>(w_ih_l0, Wb0, 300, 320);
    conv_w<<<(448 * 128 + 255) / 256, 256, 0, stream>>>(w_ih_l1, Wb1, 100, 128);
    conv_w<<<(448 * 128 + 255) / 256, 256, 0, stream>>>(w_ih_l2, Wb2, 100, 128);

    // layer 0 (embedding gather -> bf16)
    conv_a<true><<<(Mrows * 40 + 255) / 256, 256, 0, stream>>>(emb, sent, AbR, 300, 320, 40);
    gemm_mfma<<<gridG, 256, 0, stream>>>(AbR, Wb0, b_l0, xg, 320);
    lstm_scan<<<256, 256, 0, stream>>>(xg, w_hh_l0, h0 + 0 * Bb * Hh, c0 + 0 * Bb * Hh, xa16);

    // layer 1 (scan output already in bf16 [M,128] A-layout)
    gemm_mfma<<<gridG, 256, 0, stream>>>(xa16, Wb1, b_l1, xg, 128);
    lstm_scan<<<256, 256, 0, stream>>>(xg, w_hh_l1, h0 + 2 * Bb * Hh, c0 + 2 * Bb * Hh, xb16);

    // layer 2
    gemm_mfma<<<gridG, 256, 0, stream>>>(xb16, Wb2, b_l2, xg, 128);
    lstm_scan<<<256, 256, 0, stream>>>(xg, w_hh_l2, h0 + 4 * Bb * Hh, c0 + 4 * Bb * Hh, xa16);

    // tag projection + viterbi + backtrace
    feats_kernel<<<Mrows * 8 / 256, 256, 0, stream>>>(xa16, w_tag, b_tag, mask, feats);
    viterbi_fwd<<<Bb / 8, 64, 0, stream>>>(feats, trans, bptrw, out, btag);
    backtrack<<<1, 128, 0, stream>>>(bptrw, btag, out + Bb);
}

// Round 17
// 1228.651 us; speedup vs baseline: 1.1190x; 1.1190x over previous
//
#include <hip/hip_runtime.h>

#define NEGV (-10000.0f)

static constexpr int Bb    = 128;
static constexpr int Tt    = 512;
static constexpr int Mrows = Bb * Tt;   // 65536
static constexpr int Hh    = 50;
static constexpr int START = 5;

typedef __attribute__((ext_vector_type(8))) short bf16x8;
typedef __attribute__((ext_vector_type(4))) float f32x4;
typedef __attribute__((ext_vector_type(2))) _Float16 h2t;

__device__ __forceinline__ float fsig(float x) {
    return __builtin_amdgcn_rcpf(1.0f + __expf(-x));
}
__device__ __forceinline__ float ftanh(float x) {
    return 2.0f * __builtin_amdgcn_rcpf(1.0f + __expf(-2.0f * x)) - 1.0f;
}
__device__ __forceinline__ unsigned short f2bf(float f) {
    unsigned u = __float_as_uint(f);
    u = (u + 0x7fffu + ((u >> 16) & 1u)) >> 16;   // RNE
    return (unsigned short)u;
}
#define BF(u) __uint_as_float(((unsigned)(u)) << 16)

// ---------------------------------------------------------------------------
// Convert W [400][K] fp32 -> [448][KP] bf16 (zero-padded rows/cols)
// ---------------------------------------------------------------------------
__global__ __launch_bounds__(256) void conv_w(
    const float* __restrict__ src, unsigned short* __restrict__ dst,
    int K, int KP)
{
    int gid = blockIdx.x * 256 + threadIdx.x;
    int tot = 448 * KP;
    if (gid >= tot) return;
    int r = gid / KP, c = gid % KP;
    float v = (r < 400 && c < K) ? src[r * K + c] : 0.f;
    dst[gid] = f2bf(v);
}

// ---------------------------------------------------------------------------
// Convert A rows (gathered, layer 0 only) fp32 -> [M][KP] bf16
// ---------------------------------------------------------------------------
template <bool GATHER>
__global__ __launch_bounds__(256) void conv_a(
    const float* __restrict__ src, const int* __restrict__ idx,
    unsigned short* __restrict__ dst, int K, int KP, int cpr)
{
    long gid = (long)blockIdx.x * 256 + threadIdx.x;
    long tot = (long)Mrows * cpr;
    if (gid >= tot) return;
    long m = gid / cpr;
    int p = (int)(gid - m * cpr) * 8;
    const float* s = src + (GATHER ? (long)idx[m] : m) * K;
    unsigned u0, u1, u2, u3;
    {
        float x0 = (p + 0 < K) ? s[p + 0] : 0.f;
        float x1 = (p + 1 < K) ? s[p + 1] : 0.f;
        float x2 = (p + 2 < K) ? s[p + 2] : 0.f;
        float x3 = (p + 3 < K) ? s[p + 3] : 0.f;
        float x4 = (p + 4 < K) ? s[p + 4] : 0.f;
        float x5 = (p + 5 < K) ? s[p + 5] : 0.f;
        float x6 = (p + 6 < K) ? s[p + 6] : 0.f;
        float x7 = (p + 7 < K) ? s[p + 7] : 0.f;
        u0 = (unsigned)f2bf(x0) | ((unsigned)f2bf(x1) << 16);
        u1 = (unsigned)f2bf(x2) | ((unsigned)f2bf(x3) << 16);
        u2 = (unsigned)f2bf(x4) | ((unsigned)f2bf(x5) << 16);
        u3 = (unsigned)f2bf(x6) | ((unsigned)f2bf(x7) << 16);
    }
    uint4 v = make_uint4(u0, u1, u2, u3);
    *(uint4*)(dst + m * KP + p) = v;
}

// ---------------------------------------------------------------------------
// bf16 MFMA GEMM: C[M,400]bf16 = A[M,KP]bf16 @ W[448,KP]bf16^T + bias
// (unchanged from r10/r11, verified)
// ---------------------------------------------------------------------------
__global__ __launch_bounds__(256) void gemm_mfma(
    const unsigned short* __restrict__ Ab,   // [M][KP]
    const unsigned short* __restrict__ Wb,   // [448][KP]
    const float* __restrict__ bias,          // [400]
    unsigned short* __restrict__ C,          // [M][400] bf16
    int KP)
{
    __shared__ unsigned short As[128][40];
    __shared__ unsigned short Ws[64][40];

    const int tid = threadIdx.x;
    const int m0 = blockIdx.x * 128;
    const int n0 = blockIdx.y * 64;

    const int w  = tid >> 6, l = tid & 63;
    const int wm = (w >> 1) * 64;
    const int wn = (w & 1) * 32;
    const int lr = l & 15;
    const int lk = (l >> 4) * 8;

    f32x4 acc[4][2] = {};

    for (int k0 = 0; k0 < KP; k0 += 32) {
        __syncthreads();
        {
            int c = tid;
            int r = c >> 2, p = (c & 3) * 8;
            *(bf16x8*)&As[r][p] = *(const bf16x8*)(Ab + (long)(m0 + r) * KP + k0 + p);
            c = tid + 256;
            r = c >> 2; p = (c & 3) * 8;
            *(bf16x8*)&As[r][p] = *(const bf16x8*)(Ab + (long)(m0 + r) * KP + k0 + p);
            r = tid >> 2; p = (tid & 3) * 8;
            *(bf16x8*)&Ws[r][p] = *(const bf16x8*)(Wb + (long)(n0 + r) * KP + k0 + p);
        }
        __syncthreads();

        bf16x8 af0 = *(const bf16x8*)&As[wm +  0 + lr][lk];
        bf16x8 af1 = *(const bf16x8*)&As[wm + 16 + lr][lk];
        bf16x8 af2 = *(const bf16x8*)&As[wm + 32 + lr][lk];
        bf16x8 af3 = *(const bf16x8*)&As[wm + 48 + lr][lk];
        bf16x8 wf0 = *(const bf16x8*)&Ws[wn +  0 + lr][lk];
        bf16x8 wf1 = *(const bf16x8*)&Ws[wn + 16 + lr][lk];

        acc[0][0] = __builtin_amdgcn_mfma_f32_16x16x32_bf16(af0, wf0, acc[0][0], 0, 0, 0);
        acc[0][1] = __builtin_amdgcn_mfma_f32_16x16x32_bf16(af0, wf1, acc[0][1], 0, 0, 0);
        acc[1][0] = __builtin_amdgcn_mfma_f32_16x16x32_bf16(af1, wf0, acc[1][0], 0, 0, 0);
        acc[1][1] = __builtin_amdgcn_mfma_f32_16x16x32_bf16(af1, wf1, acc[1][1], 0, 0, 0);
        acc[2][0] = __builtin_amdgcn_mfma_f32_16x16x32_bf16(af2, wf0, acc[2][0], 0, 0, 0);
        acc[2][1] = __builtin_amdgcn_mfma_f32_16x16x32_bf16(af2, wf1, acc[2][1], 0, 0, 0);
        acc[3][0] = __builtin_amdgcn_mfma_f32_16x16x32_bf16(af3, wf0, acc[3][0], 0, 0, 0);
        acc[3][1] = __builtin_amdgcn_mfma_f32_16x16x32_bf16(af3, wf1, acc[3][1], 0, 0, 0);
    }

    const int orow = (l >> 4) * 4;
    const int ocol = l & 15;
    #pragma unroll
    for (int a = 0; a < 4; ++a) {
        #pragma unroll
        for (int bb = 0; bb < 2; ++bb) {
            const int col = n0 + wn + bb * 16 + ocol;
            if (col < 400) {
                const float bv = bias[col];
                #pragma unroll
                for (int i = 0; i < 4; ++i) {
                    const long row = m0 + wm + a * 16 + orow + i;
                    C[row * 400 + col] = f2bf(acc[a][bb][i] + bv);
                }
            }
        }
    }
}

// ---------------------------------------------------------------------------
// LSTM scan: hybrid of the two proven variants.
//  - dot phase (r16, verified): thread t<200 owns gate row t as 25 packed
//    fp16 pairs -> 25 readlane + 25 v_dot2 (half of r15's 100-op issue).
//  - activation phase (r15, verified): lanes 0-49, ONE unit each (4 exp,
//    shortest chain; r16's 2-units/lane serial chain caused the regression).
//  - bridge: after activation every lane packs hpk = cvt_pkrtz(
//    readlane(hreg,2k), readlane(hreg,2k+1)), k=min(lane,24) -> the h2
//    pair lands in lane k where the dot phase's readlane(hpki,K) expects
//    it. readlane-only (no bpermute -> avoids r14's NaN path).
//  - output path identical to r15 (bf16 scatter into [M,128] A-layout).
// ---------------------------------------------------------------------------
#if __has_builtin(__builtin_amdgcn_fdot2)
#define DOT2(W, HH, A) A = __builtin_amdgcn_fdot2(W, HH, A, false)
#else
#define DOT2(W, HH, A) A += (float)(W).x * (float)(HH).x + (float)(W).y * (float)(HH).y
#endif

#define LDW(P, Q) __builtin_bit_cast(unsigned, (h2t){(_Float16)(P)[2*(Q)], (_Float16)(P)[2*(Q)+1]})
#define PKH(A, B) __builtin_bit_cast(h2t, __builtin_amdgcn_cvt_pkrtz((A), (B)))
#define LA10(x0,x1,x2,x3,x4,x5,x6,x7,x8,x9) \
    asm volatile("" : "+v"(x0), "+v"(x1), "+v"(x2), "+v"(x3), "+v"(x4), \
                      "+v"(x5), "+v"(x6), "+v"(x7), "+v"(x8), "+v"(x9))
#define LA5(x0,x1,x2,x3,x4) \
    asm volatile("" : "+v"(x0), "+v"(x1), "+v"(x2), "+v"(x3), "+v"(x4))

__global__ void
__attribute__((amdgpu_flat_work_group_size(256, 256), amdgpu_waves_per_eu(1, 1)))
lstm_scan(
    const unsigned short* __restrict__ xg,  // [M,400] bf16 (bias added)
    const float* __restrict__ w_hh,         // [2,200,50]
    const float* __restrict__ h0,           // layer base: [2,B,50]
    const float* __restrict__ c0,
    unsigned short* __restrict__ xout)      // [M,128] bf16, cols 100-127 = 0
{
    const int b    = blockIdx.x & 127;
    const int dir  = blockIdx.x >> 7;
    const int tid  = threadIdx.x;
    const int lane = tid & 63;
    const int wv   = tid >> 6;

    __shared__ float pre[2][200];   // double-buffered pre-gates (only LDS)

    const int gr = (tid < 200) ? tid : 199;

    const float* wr = w_hh + ((long)dir * 200 + gr) * 50;
    unsigned W0=LDW(wr,0), W1=LDW(wr,1), W2=LDW(wr,2), W3=LDW(wr,3), W4=LDW(wr,4);
    unsigned W5=LDW(wr,5), W6=LDW(wr,6), W7=LDW(wr,7), W8=LDW(wr,8), W9=LDW(wr,9);
    unsigned W10=LDW(wr,10),W11=LDW(wr,11),W12=LDW(wr,12),W13=LDW(wr,13),W14=LDW(wr,14);
    unsigned W15=LDW(wr,15),W16=LDW(wr,16),W17=LDW(wr,17),W18=LDW(wr,18),W19=LDW(wr,19);
    unsigned W20=LDW(wr,20),W21=LDW(wr,21),W22=LDW(wr,22),W23=LDW(wr,23),W24=LDW(wr,24);
    LA10(W0,W1,W2,W3,W4,W5,W6,W7,W8,W9);
    LA10(W10,W11,W12,W13,W14,W15,W16,W17,W18,W19);
    LA5(W20,W21,W22,W23,W24);

    // h, c: lanes 0-49 of EVERY wave own one unit (redundant across waves)
    float hreg = 0.f, c = 0.f;
    if (lane < 50) {
        c    = c0[((long)dir * Bb + b) * Hh + lane];
        hreg = h0[((long)dir * Bb + b) * Hh + lane];
    }
    // initial pack: lane k<25 gets (h[2k], h[2k+1]) via readlane
    const int upk = (lane < 25) ? lane : 24;
    #define HREADL(J) __uint_as_float((unsigned)__builtin_amdgcn_readlane((int)__float_as_uint(hreg), (J)))
    h2t hpk = PKH(HREADL(2 * upk), HREADL(2 * upk + 1));
    __syncthreads();

    const long rowbase = (long)b * Tt;
    const unsigned short* xbase = xg + rowbase * 400 + dir * 200 + gr;
    // output col: units -> dir*50+lane; pad cols 100-127 split across dirs
    const int ocol = (lane < 50) ? (dir * 50 + lane) : (100 + dir * 14 + (lane - 50));
    unsigned short* op = xout + rowbase * 128 + ocol;

    #define XLD(s)  xbase[(long)(dir ? (Tt - 1 - (s)) : (s)) * 400]
    #define TTOF(s) (dir ? (Tt - 1 - (s)) : (s))

    #define DD(K, ACC) { \
        h2t hh = __builtin_bit_cast(h2t, (unsigned)__builtin_amdgcn_readlane(hpki, K)); \
        DOT2(__builtin_bit_cast(h2t, W##K), hh, ACC); }

    #define STEP(PRE, XIN, TT) do {                                         \
        if (tid < 200) {                                                    \
            float s0 = BF(XIN), s1 = 0.f;                                   \
            const int hpki = (int)__builtin_bit_cast(unsigned, hpk);        \
            DD(0,s0)  DD(1,s1)  DD(2,s0)  DD(3,s1)  DD(4,s0)                \
            DD(5,s1)  DD(6,s0)  DD(7,s1)  DD(8,s0)  DD(9,s1)                \
            DD(10,s0) DD(11,s1) DD(12,s0) DD(13,s1) DD(14,s0)               \
            DD(15,s1) DD(16,s0) DD(17,s1) DD(18,s0) DD(19,s1)               \
            DD(20,s0) DD(21,s1) DD(22,s0) DD(23,s1) DD(24,s0)               \
            (PRE)[tid] = s0 + s1;                                           \
        }                                                                   \
        asm volatile("s_waitcnt lgkmcnt(0)\n\ts_barrier" ::: "memory");     \
        {                                                                   \
            unsigned short val = 0;                                         \
            if (lane < 50) {                                                \
                const float gi = fsig((PRE)[lane]);                         \
                const float gf = fsig((PRE)[50 + lane]);                    \
                const float gc = ftanh((PRE)[100 + lane]);                  \
                const float go = fsig((PRE)[150 + lane]);                   \
                c = gf * c + gi * gc;                                       \
                hreg = go * ftanh(c);                                       \
                val = f2bf(hreg);                                           \
            }                                                               \
            if (wv == 0) op[(long)(TT) * 128] = val;                        \
            hpk = PKH(HREADL(2 * upk), HREADL(2 * upk + 1));                \
        }                                                                   \
    } while (0)

    unsigned xc0 = XLD(0), xc1 = XLD(1), xc2 = XLD(2), xc3 = XLD(3);
    unsigned xn0 = 0, xn1 = 0, xn2 = 0, xn3 = 0;

    for (int blk = 0; blk < Tt / 4; ++blk) {
        const int s0i = blk * 4;
        if (blk < Tt / 4 - 1) {
            xn0 = XLD(s0i + 4); xn1 = XLD(s0i + 5);
            xn2 = XLD(s0i + 6); xn3 = XLD(s0i + 7);
        }
        STEP(pre[0], xc0, TTOF(s0i + 0));
        STEP(pre[1], xc1, TTOF(s0i + 1));
        STEP(pre[0], xc2, TTOF(s0i + 2));
        STEP(pre[1], xc3, TTOF(s0i + 3));
        xc0 = xn0; xc1 = xn1; xc2 = xn2; xc3 = xn3;
    }
    #undef STEP
    #undef DD
    #undef XLD
    #undef TTOF
    #undef HREADL
}

// ---------------------------------------------------------------------------
// feats[row, i] = (x_bf16[row,:100] . w_tag[i,:] + b_tag[i]) * mask[row]
// ---------------------------------------------------------------------------
__global__ __launch_bounds__(256) void feats_kernel(
    const unsigned short* __restrict__ x, // [M,128] bf16
    const float* __restrict__ w_tag,      // [7,100]
    const float* __restrict__ b_tag,      // [7]
    const float* __restrict__ mask,       // [M]
    float* __restrict__ feats)            // [M,8]
{
    const int gid = blockIdx.x * 256 + threadIdx.x;
    const int row = gid >> 3;
    const int i   = gid & 7;
    if (row >= Mrows) return;
    if (i == 7) { feats[(long)row * 8 + 7] = 0.f; return; }
    const unsigned* xr = (const unsigned*)(x + (long)row * 128); // 2 bf16/word
    const float* wr = w_tag + i * 100;
    float acc = b_tag[i];
    #pragma unroll
    for (int q = 0; q < 50; ++q) {
        unsigned v = xr[q];
        float2 w2 = *(const float2*)(wr + 2 * q);
        acc += __uint_as_float(v << 16) * w2.x
             + __uint_as_float(v & 0xffff0000u) * w2.y;
    }
    feats[(long)row * 8 + i] = acc * mask[row];
}

// ---------------------------------------------------------------------------
// Viterbi forward. 8 lanes per batch row; backpointers packed [T][B].
// ---------------------------------------------------------------------------
__global__ __launch_bounds__(64) void viterbi_fwd(
    const float* __restrict__ feats,   // [M,8]
    const float* __restrict__ trans,   // [7,7]
    unsigned int* __restrict__ bptrw,  // [T*B]
    float* __restrict__ best_score,    // [B] -> d_out
    int* __restrict__ best_tag)        // [B] -> ws
{
    const int lane = threadIdx.x;
    const int sub  = lane >> 3;
    const int i    = lane & 7;
    const int b    = blockIdx.x * 8 + sub;
    const int base = lane & 56;

    float tr[7];
    #pragma unroll
    for (int j = 0; j < 7; ++j) tr[j] = (i < 7) ? trans[i * 7 + j] : -1e30f;

    float score = (i == START) ? 0.0f : NEGV;
    const long fb = (long)b * Tt;

    float featc = feats[(fb + 0) * 8 + i];
    for (int t = 0; t < Tt; ++t) {
        float featn = (t + 1 < Tt) ? feats[(fb + t + 1) * 8 + i] : 0.f;
        float best = -3.4e38f;
        int bp = 0;
        #pragma unroll
        for (int j = 0; j < 7; ++j) {
            float sj = __shfl(score, base | j, 64);
            float m = sj + tr[j];
            if (m > best) { best = m; bp = j; }
        }
        if (i < 7) score = best + featc;
        unsigned v = (i < 7) ? ((unsigned)bp << (3 * i)) : 0u;
        v |= __shfl_xor(v, 1, 64);
        v |= __shfl_xor(v, 2, 64);
        v |= __shfl_xor(v, 4, 64);
        if (i == 0) bptrw[(long)t * Bb + b] = v;
        featc = featn;
    }

    float bestv = score;
    int bt = 0;
    #pragma unroll
    for (int j = 1; j < 7; ++j) {
        float sj = __shfl(score, base | j, 64);
        if (i == 0 && sj > bestv) { bestv = sj; bt = j; }
    }
    if (i == 0) {
        best_score[b] = bestv;
        best_tag[b]   = bt;
    }
}

// ---------------------------------------------------------------------------
__global__ __launch_bounds__(128) void backtrack(
    const unsigned int* __restrict__ bptrw,
    const int* __restrict__ best_tag,
    float* __restrict__ out_tags)   // d_out + 128, [B,T]
{
    const int b = threadIdx.x;
    if (b >= Bb) return;
    const long fb = (long)b * Tt;
    int tag = best_tag[b];
    out_tags[fb + Tt - 1] = (float)tag;
    #pragma unroll 8
    for (int t = Tt - 1; t >= 1; --t) {
        unsigned w = bptrw[(long)t * Bb + b];
        tag = (w >> (3 * tag)) & 7;
        out_tags[fb + t - 1] = (float)tag;
    }
}

// ---------------------------------------------------------------------------
extern "C" void kernel_launch(void* const* d_in, const int* in_sizes, int n_in,
                              void* d_out, int out_size, void* d_ws, size_t ws_size,
                              hipStream_t stream)
{
    const int*   sent    = (const int*)  d_in[0];
    const float* mask    = (const float*)d_in[1];
    const float* emb     = (const float*)d_in[2];
    const float* h0      = (const float*)d_in[3];
    const float* c0      = (const float*)d_in[4];
    const float* w_ih_l0 = (const float*)d_in[5];
    const float* w_hh_l0 = (const float*)d_in[6];
    const float* b_l0    = (const float*)d_in[7];
    const float* w_ih_l1 = (const float*)d_in[8];
    const float* w_hh_l1 = (const float*)d_in[9];
    const float* b_l1    = (const float*)d_in[10];
    const float* w_ih_l2 = (const float*)d_in[11];
    const float* w_hh_l2 = (const float*)d_in[12];
    const float* b_l2    = (const float*)d_in[13];
    const float* w_tag   = (const float*)d_in[14];
    const float* b_tag   = (const float*)d_in[15];
    const float* trans   = (const float*)d_in[16];

    float* out = (float*)d_out;
    char* ws = (char*)d_ws;

    // workspace layout (bytes)
    unsigned short* xg    = (unsigned short*)(ws);                  // 52,428,800
    unsigned short* xa16  = (unsigned short*)(ws + 52428800L);      // 16,777,216
    unsigned short* xb16  = (unsigned short*)(ws + 69206016L);      // 16,777,216
    unsigned short* AbR   = (unsigned short*)(ws + 85983232L);      // 41,943,040
    float*          feats = (float*)(ws + 127926272L);              //  2,097,152
    unsigned*       bptrw = (unsigned*)(ws + 130023424L);           //    262,144
    unsigned short* Wb0   = (unsigned short*)(ws + 130285568L);     //    286,720
    unsigned short* Wb1   = (unsigned short*)(ws + 130572288L);     //    114,688
    unsigned short* Wb2   = (unsigned short*)(ws + 130686976L);     //    114,688
    int*            btag  = (int*)(ws + 130801664L);                //        512

    dim3 gridG(Mrows / 128, 7);   // 128x64 tiles over [65536, 448]

    // weight conversions (independent)
    conv_w<<<(448 * 320 + 255) / 256, 256, 0, stream>>>(w_ih_l0, Wb0, 300, 320);
    conv_w<<<(448 * 128 + 255) / 256, 256, 0, stream>>>(w_ih_l1, Wb1, 100, 128);
    conv_w<<<(448 * 128 + 255) / 256, 256, 0, stream>>>(w_ih_l2, Wb2, 100, 128);

    // layer 0 (embedding gather -> bf16)
    conv_a<true><<<(Mrows * 40 + 255) / 256, 256, 0, stream>>>(emb, sent, AbR, 300, 320, 40);
    gemm_mfma<<<gridG, 256, 0, stream>>>(AbR, Wb0, b_l0, xg, 320);
    lstm_scan<<<256, 256, 0, stream>>>(xg, w_hh_l0, h0 + 0 * Bb * Hh, c0 + 0 * Bb * Hh, xa16);

    // layer 1 (scan output already in bf16 [M,128] A-layout)
    gemm_mfma<<<gridG, 256, 0, stream>>>(xa16, Wb1, b_l1, xg, 128);
    lstm_scan<<<256, 256, 0, stream>>>(xg, w_hh_l1, h0 + 2 * Bb * Hh, c0 + 2 * Bb * Hh, xb16);

    // layer 2
    gemm_mfma<<<gridG, 256, 0, stream>>>(xb16, Wb2, b_l2, xg, 128);
    lstm_scan<<<256, 256, 0, stream>>>(xg, w_hh_l2, h0 + 4 * Bb * Hh, c0 + 4 * Bb * Hh, xa16);

    // tag projection + viterbi + backtrace
    feats_kernel<<<Mrows * 8 / 256, 256, 0, stream>>>(xa16, w_tag, b_tag, mask, feats);
    viterbi_fwd<<<Bb / 8, 64, 0, stream>>>(feats, trans, bptrw, out, btag);
    backtrack<<<1, 128, 0, stream>>>(bptrw, btag, out + Bb);
}

// Round 18
// 1191.694 us; speedup vs baseline: 1.1537x; 1.0310x over previous
//
#include <hip/hip_runtime.h>

#define NEGV (-10000.0f)

static constexpr int Bb    = 128;
static constexpr int Tt    = 512;
static constexpr int Mrows = Bb * Tt;   // 65536
static constexpr int Hh    = 50;
static constexpr int START = 5;

typedef __attribute__((ext_vector_type(8))) short bf16x8;
typedef __attribute__((ext_vector_type(4))) float f32x4;

__device__ __forceinline__ float fsig(float x) {
    return __builtin_amdgcn_rcpf(1.0f + __expf(-x));
}
__device__ __forceinline__ float ftanh(float x) {
    return 2.0f * __builtin_amdgcn_rcpf(1.0f + __expf(-2.0f * x)) - 1.0f;
}
__device__ __forceinline__ unsigned short f2bf(float f) {
    unsigned u = __float_as_uint(f);
    u = (u + 0x7fffu + ((u >> 16) & 1u)) >> 16;   // RNE
    return (unsigned short)u;
}
#define BF(u) __uint_as_float(((unsigned)(u)) << 16)

// ---------------------------------------------------------------------------
// Fused weight conversion for all three layers (one launch instead of three)
// ---------------------------------------------------------------------------
__global__ __launch_bounds__(256) void conv_w3(
    const float* __restrict__ s0, const float* __restrict__ s1,
    const float* __restrict__ s2,
    unsigned short* __restrict__ d0, unsigned short* __restrict__ d1,
    unsigned short* __restrict__ d2)
{
    int gid = blockIdx.x * 256 + threadIdx.x;
    const float* src; unsigned short* dst; int K, KP, off;
    if (gid < 143360)      { src = s0; dst = d0; K = 300; KP = 320; off = gid; }
    else if (gid < 200704) { src = s1; dst = d1; K = 100; KP = 128; off = gid - 143360; }
    else if (gid < 258048) { src = s2; dst = d2; K = 100; KP = 128; off = gid - 200704; }
    else return;
    int r = off / KP, c = off % KP;
    float v = (r < 400 && c < K) ? src[r * K + c] : 0.f;
    dst[off] = f2bf(v);
}

// ---------------------------------------------------------------------------
// Convert A rows (gathered, layer 0 only) fp32 -> [M][KP] bf16
// ---------------------------------------------------------------------------
template <bool GATHER>
__global__ __launch_bounds__(256) void conv_a(
    const float* __restrict__ src, const int* __restrict__ idx,
    unsigned short* __restrict__ dst, int K, int KP, int cpr)
{
    long gid = (long)blockIdx.x * 256 + threadIdx.x;
    long tot = (long)Mrows * cpr;
    if (gid >= tot) return;
    long m = gid / cpr;
    int p = (int)(gid - m * cpr) * 8;
    const float* s = src + (GATHER ? (long)idx[m] : m) * K;
    unsigned u0, u1, u2, u3;
    {
        float x0 = (p + 0 < K) ? s[p + 0] : 0.f;
        float x1 = (p + 1 < K) ? s[p + 1] : 0.f;
        float x2 = (p + 2 < K) ? s[p + 2] : 0.f;
        float x3 = (p + 3 < K) ? s[p + 3] : 0.f;
        float x4 = (p + 4 < K) ? s[p + 4] : 0.f;
        float x5 = (p + 5 < K) ? s[p + 5] : 0.f;
        float x6 = (p + 6 < K) ? s[p + 6] : 0.f;
        float x7 = (p + 7 < K) ? s[p + 7] : 0.f;
        u0 = (unsigned)f2bf(x0) | ((unsigned)f2bf(x1) << 16);
        u1 = (unsigned)f2bf(x2) | ((unsigned)f2bf(x3) << 16);
        u2 = (unsigned)f2bf(x4) | ((unsigned)f2bf(x5) << 16);
        u3 = (unsigned)f2bf(x6) | ((unsigned)f2bf(x7) << 16);
    }
    uint4 v = make_uint4(u0, u1, u2, u3);
    *(uint4*)(dst + m * KP + p) = v;
}

// ---------------------------------------------------------------------------
// bf16 MFMA GEMM: C[M,400]bf16 = A[M,KP]bf16 @ W[448,KP]bf16^T + bias
// (unchanged from r10/r11, verified)
// ---------------------------------------------------------------------------
__global__ __launch_bounds__(256) void gemm_mfma(
    const unsigned short* __restrict__ Ab,   // [M][KP]
    const unsigned short* __restrict__ Wb,   // [448][KP]
    const float* __restrict__ bias,          // [400]
    unsigned short* __restrict__ C,          // [M][400] bf16
    int KP)
{
    __shared__ unsigned short As[128][40];
    __shared__ unsigned short Ws[64][40];

    const int tid = threadIdx.x;
    const int m0 = blockIdx.x * 128;
    const int n0 = blockIdx.y * 64;

    const int w  = tid >> 6, l = tid & 63;
    const int wm = (w >> 1) * 64;
    const int wn = (w & 1) * 32;
    const int lr = l & 15;
    const int lk = (l >> 4) * 8;

    f32x4 acc[4][2] = {};

    for (int k0 = 0; k0 < KP; k0 += 32) {
        __syncthreads();
        {
            int c = tid;
            int r = c >> 2, p = (c & 3) * 8;
            *(bf16x8*)&As[r][p] = *(const bf16x8*)(Ab + (long)(m0 + r) * KP + k0 + p);
            c = tid + 256;
            r = c >> 2; p = (c & 3) * 8;
            *(bf16x8*)&As[r][p] = *(const bf16x8*)(Ab + (long)(m0 + r) * KP + k0 + p);
            r = tid >> 2; p = (tid & 3) * 8;
            *(bf16x8*)&Ws[r][p] = *(const bf16x8*)(Wb + (long)(n0 + r) * KP + k0 + p);
        }
        __syncthreads();

        bf16x8 af0 = *(const bf16x8*)&As[wm +  0 + lr][lk];
        bf16x8 af1 = *(const bf16x8*)&As[wm + 16 + lr][lk];
        bf16x8 af2 = *(const bf16x8*)&As[wm + 32 + lr][lk];
        bf16x8 af3 = *(const bf16x8*)&As[wm + 48 + lr][lk];
        bf16x8 wf0 = *(const bf16x8*)&Ws[wn +  0 + lr][lk];
        bf16x8 wf1 = *(const bf16x8*)&Ws[wn + 16 + lr][lk];

        acc[0][0] = __builtin_amdgcn_mfma_f32_16x16x32_bf16(af0, wf0, acc[0][0], 0, 0, 0);
        acc[0][1] = __builtin_amdgcn_mfma_f32_16x16x32_bf16(af0, wf1, acc[0][1], 0, 0, 0);
        acc[1][0] = __builtin_amdgcn_mfma_f32_16x16x32_bf16(af1, wf0, acc[1][0], 0, 0, 0);
        acc[1][1] = __builtin_amdgcn_mfma_f32_16x16x32_bf16(af1, wf1, acc[1][1], 0, 0, 0);
        acc[2][0] = __builtin_amdgcn_mfma_f32_16x16x32_bf16(af2, wf0, acc[2][0], 0, 0, 0);
        acc[2][1] = __builtin_amdgcn_mfma_f32_16x16x32_bf16(af2, wf1, acc[2][1], 0, 0, 0);
        acc[3][0] = __builtin_amdgcn_mfma_f32_16x16x32_bf16(af3, wf0, acc[3][0], 0, 0, 0);
        acc[3][1] = __builtin_amdgcn_mfma_f32_16x16x32_bf16(af3, wf1, acc[3][1], 0, 0, 0);
    }

    const int orow = (l >> 4) * 4;
    const int ocol = l & 15;
    #pragma unroll
    for (int a = 0; a < 4; ++a) {
        #pragma unroll
        for (int bb = 0; bb < 2; ++bb) {
            const int col = n0 + wn + bb * 16 + ocol;
            if (col < 400) {
                const float bv = bias[col];
                #pragma unroll
                for (int i = 0; i < 4; ++i) {
                    const long row = m0 + wm + a * 16 + orow + i;
                    C[row * 400 + col] = f2bf(acc[a][bb][i] + bv);
                }
            }
        }
    }
}

// ---------------------------------------------------------------------------
// LSTM scan: r15 exact (verified 280us, absmax 2.0): 4 waves, gate-major,
// 50 laundered fp32 scalar weights/thread, h via v_readlane (immediate
// index), pre[2][200] double-buffered, one raw s_barrier/step (lgkm-only
// drain), bf16 output into [M,128] padded GEMM A-layout.
// Scan family is at its structural floor (~1250cy/step across 8 variants);
// do not touch further.
// ---------------------------------------------------------------------------
#define H(J) __uint_as_float((unsigned)__builtin_amdgcn_readlane((int)__float_as_uint(hreg), (J)))

__global__ void
__attribute__((amdgpu_flat_work_group_size(256, 256), amdgpu_waves_per_eu(1, 1)))
lstm_scan(
    const unsigned short* __restrict__ xg,  // [M,400] bf16 (bias added)
    const float* __restrict__ w_hh,         // [2,200,50]
    const float* __restrict__ h0,           // layer base: [2,B,50]
    const float* __restrict__ c0,
    unsigned short* __restrict__ xout)      // [M,128] bf16, cols 100-127 = 0
{
    const int b    = blockIdx.x & 127;
    const int dir  = blockIdx.x >> 7;
    const int tid  = threadIdx.x;
    const int lane = tid & 63;
    const int wv   = tid >> 6;

    __shared__ float pre[2][200];   // double-buffered pre-gates (only LDS)

    const int gr = (tid < 200) ? tid : 199;

    const float* wr = w_hh + ((long)dir * 200 + gr) * 50;
    float w0  = wr[0],  w1  = wr[1],  w2  = wr[2],  w3  = wr[3],  w4  = wr[4];
    float w5  = wr[5],  w6  = wr[6],  w7  = wr[7],  w8  = wr[8],  w9  = wr[9];
    float w10 = wr[10], w11 = wr[11], w12 = wr[12], w13 = wr[13], w14 = wr[14];
    float w15 = wr[15], w16 = wr[16], w17 = wr[17], w18 = wr[18], w19 = wr[19];
    float w20 = wr[20], w21 = wr[21], w22 = wr[22], w23 = wr[23], w24 = wr[24];
    float w25 = wr[25], w26 = wr[26], w27 = wr[27], w28 = wr[28], w29 = wr[29];
    float w30 = wr[30], w31 = wr[31], w32 = wr[32], w33 = wr[33], w34 = wr[34];
    float w35 = wr[35], w36 = wr[36], w37 = wr[37], w38 = wr[38], w39 = wr[39];
    float w40 = wr[40], w41 = wr[41], w42 = wr[42], w43 = wr[43], w44 = wr[44];
    float w45 = wr[45], w46 = wr[46], w47 = wr[47], w48 = wr[48], w49 = wr[49];
    asm volatile("" : "+v"(w0), "+v"(w1), "+v"(w2), "+v"(w3), "+v"(w4),
                      "+v"(w5), "+v"(w6), "+v"(w7), "+v"(w8), "+v"(w9));
    asm volatile("" : "+v"(w10), "+v"(w11), "+v"(w12), "+v"(w13), "+v"(w14),
                      "+v"(w15), "+v"(w16), "+v"(w17), "+v"(w18), "+v"(w19));
    asm volatile("" : "+v"(w20), "+v"(w21), "+v"(w22), "+v"(w23), "+v"(w24),
                      "+v"(w25), "+v"(w26), "+v"(w27), "+v"(w28), "+v"(w29));
    asm volatile("" : "+v"(w30), "+v"(w31), "+v"(w32), "+v"(w33), "+v"(w34),
                      "+v"(w35), "+v"(w36), "+v"(w37), "+v"(w38), "+v"(w39));
    asm volatile("" : "+v"(w40), "+v"(w41), "+v"(w42), "+v"(w43), "+v"(w44),
                      "+v"(w45), "+v"(w46), "+v"(w47), "+v"(w48), "+v"(w49));

    // h and c live in registers of lanes 0-49 of EVERY wave (redundant).
    float hreg = 0.f, c = 0.f;
    if (lane < 50) {
        c    = c0[((long)dir * Bb + b) * Hh + lane];
        hreg = h0[((long)dir * Bb + b) * Hh + lane];
    }
    __syncthreads();

    const long rowbase = (long)b * Tt;
    const unsigned short* xbase = xg + rowbase * 400 + dir * 200 + gr;
    // output col: units -> dir*50+lane; pad cols 100-127 split across dirs
    const int ocol = (lane < 50) ? (dir * 50 + lane) : (100 + dir * 14 + (lane - 50));
    unsigned short* op = xout + rowbase * 128 + ocol;

    #define XLD(s)  xbase[(long)(dir ? (Tt - 1 - (s)) : (s)) * 400]
    #define TTOF(s) (dir ? (Tt - 1 - (s)) : (s))

    #define STEP(PRE, XIN, TT) do {                                         \
        if (tid < 200) {                                                    \
            float s0 = BF(XIN), s1 = 0.f, s2 = 0.f, s3 = 0.f;               \
            s0 += w0 *H(0);  s1 += w1 *H(1);  s2 += w2 *H(2);  s3 += w3 *H(3);  \
            s0 += w4 *H(4);  s1 += w5 *H(5);  s2 += w6 *H(6);  s3 += w7 *H(7);  \
            s0 += w8 *H(8);  s1 += w9 *H(9);  s2 += w10*H(10); s3 += w11*H(11); \
            s0 += w12*H(12); s1 += w13*H(13); s2 += w14*H(14); s3 += w15*H(15); \
            s0 += w16*H(16); s1 += w17*H(17); s2 += w18*H(18); s3 += w19*H(19); \
            s0 += w20*H(20); s1 += w21*H(21); s2 += w22*H(22); s3 += w23*H(23); \
            s0 += w24*H(24); s1 += w25*H(25); s2 += w26*H(26); s3 += w27*H(27); \
            s0 += w28*H(28); s1 += w29*H(29); s2 += w30*H(30); s3 += w31*H(31); \
            s0 += w32*H(32); s1 += w33*H(33); s2 += w34*H(34); s3 += w35*H(35); \
            s0 += w36*H(36); s1 += w37*H(37); s2 += w38*H(38); s3 += w39*H(39); \
            s0 += w40*H(40); s1 += w41*H(41); s2 += w42*H(42); s3 += w43*H(43); \
            s0 += w44*H(44); s1 += w45*H(45); s2 += w46*H(46); s3 += w47*H(47); \
            s0 += w48*H(48); s1 += w49*H(49);                               \
            (PRE)[tid] = (s0 + s1) + (s2 + s3);                             \
        }                                                                   \
        asm volatile("s_waitcnt lgkmcnt(0)\n\ts_barrier" ::: "memory");     \
        {                                                                   \
            unsigned short val = 0;                                         \
            if (lane < 50) {                                                \
                const float gi = fsig((PRE)[lane]);                         \
                const float gf = fsig((PRE)[50 + lane]);                    \
                const float gc = ftanh((PRE)[100 + lane]);                  \
                const float go = fsig((PRE)[150 + lane]);                   \
                c = gf * c + gi * gc;                                       \
                hreg = go * ftanh(c);                                       \
                val = f2bf(hreg);                                           \
            }                                                               \
            if (wv == 0) op[(long)(TT) * 128] = val;                        \
        }                                                                   \
    } while (0)

    unsigned xc0 = XLD(0), xc1 = XLD(1), xc2 = XLD(2), xc3 = XLD(3);
    unsigned xn0 = 0, xn1 = 0, xn2 = 0, xn3 = 0;

    for (int blk = 0; blk < Tt / 4; ++blk) {
        const int s0i = blk * 4;
        if (blk < Tt / 4 - 1) {
            xn0 = XLD(s0i + 4); xn1 = XLD(s0i + 5);
            xn2 = XLD(s0i + 6); xn3 = XLD(s0i + 7);
        }
        STEP(pre[0], xc0, TTOF(s0i + 0));
        STEP(pre[1], xc1, TTOF(s0i + 1));
        STEP(pre[0], xc2, TTOF(s0i + 2));
        STEP(pre[1], xc3, TTOF(s0i + 3));
        xc0 = xn0; xc1 = xn1; xc2 = xn2; xc3 = xn3;
    }
    #undef STEP
    #undef XLD
    #undef TTOF
}

// ---------------------------------------------------------------------------
// feats[row, i] = (x_bf16[row,:100] . w_tag[i,:] + b_tag[i]) * mask[row]
// ---------------------------------------------------------------------------
__global__ __launch_bounds__(256) void feats_kernel(
    const unsigned short* __restrict__ x, // [M,128] bf16
    const float* __restrict__ w_tag,      // [7,100]
    const float* __restrict__ b_tag,      // [7]
    const float* __restrict__ mask,       // [M]
    float* __restrict__ feats)            // [M,8]
{
    const int gid = blockIdx.x * 256 + threadIdx.x;
    const int row = gid >> 3;
    const int i   = gid & 7;
    if (row >= Mrows) return;
    if (i == 7) { feats[(long)row * 8 + 7] = 0.f; return; }
    const unsigned* xr = (const unsigned*)(x + (long)row * 128); // 2 bf16/word
    const float* wr = w_tag + i * 100;
    float acc = b_tag[i];
    #pragma unroll
    for (int q = 0; q < 50; ++q) {
        unsigned v = xr[q];
        float2 w2 = *(const float2*)(wr + 2 * q);
        acc += __uint_as_float(v << 16) * w2.x
             + __uint_as_float(v & 0xffff0000u) * w2.y;
    }
    feats[(long)row * 8 + i] = acc * mask[row];
}

// ---------------------------------------------------------------------------
// Viterbi forward. 8 lanes per batch row; backpointers packed [T][B].
// 4-deep feats prefetch: loads are address-independent of the recurrence,
// so 4 stay in flight and cover the ~300cy L2/HBM latency that the 1-deep
// version exposed every step.
// ---------------------------------------------------------------------------
__global__ __launch_bounds__(64) void viterbi_fwd(
    const float* __restrict__ feats,   // [M,8]
    const float* __restrict__ trans,   // [7,7]
    unsigned int* __restrict__ bptrw,  // [T*B]
    float* __restrict__ best_score,    // [B] -> d_out
    int* __restrict__ best_tag)        // [B] -> ws
{
    const int lane = threadIdx.x;
    const int sub  = lane >> 3;
    const int i    = lane & 7;
    const int b    = blockIdx.x * 8 + sub;
    const int base = lane & 56;

    float tr[7];
    #pragma unroll
    for (int j = 0; j < 7; ++j) tr[j] = (i < 7) ? trans[i * 7 + j] : -1e30f;

    float score = (i == START) ? 0.0f : NEGV;
    const long fb = (long)b * Tt;

    float ft0 = feats[(fb + 0) * 8 + i];
    float ft1 = feats[(fb + 1) * 8 + i];
    float ft2 = feats[(fb + 2) * 8 + i];
    float ft3 = feats[(fb + 3) * 8 + i];

    for (int t = 0; t < Tt; ++t) {
        const float ftn = (t + 4 < Tt) ? feats[(fb + t + 4) * 8 + i] : 0.f;
        float best = -3.4e38f;
        int bp = 0;
        #pragma unroll
        for (int j = 0; j < 7; ++j) {
            float sj = __shfl(score, base | j, 64);
            float m = sj + tr[j];
            if (m > best) { best = m; bp = j; }   // strict > : first-tie like argmax
        }
        if (i < 7) score = best + ft0;
        unsigned v = (i < 7) ? ((unsigned)bp << (3 * i)) : 0u;
        v |= __shfl_xor(v, 1, 64);
        v |= __shfl_xor(v, 2, 64);
        v |= __shfl_xor(v, 4, 64);
        if (i == 0) bptrw[(long)t * Bb + b] = v;
        ft0 = ft1; ft1 = ft2; ft2 = ft3; ft3 = ftn;
    }

    float bestv = score;
    int bt = 0;
    #pragma unroll
    for (int j = 1; j < 7; ++j) {
        float sj = __shfl(score, base | j, 64);
        if (i == 0 && sj > bestv) { bestv = sj; bt = j; }
    }
    if (i == 0) {
        best_score[b] = bestv;
        best_tag[b]   = bt;
    }
}

// ---------------------------------------------------------------------------
__global__ __launch_bounds__(128) void backtrack(
    const unsigned int* __restrict__ bptrw,
    const int* __restrict__ best_tag,
    float* __restrict__ out_tags)   // d_out + 128, [B,T]
{
    const int b = threadIdx.x;
    if (b >= Bb) return;
    const long fb = (long)b * Tt;
    int tag = best_tag[b];
    out_tags[fb + Tt - 1] = (float)tag;
    #pragma unroll 8
    for (int t = Tt - 1; t >= 1; --t) {
        unsigned w = bptrw[(long)t * Bb + b];
        tag = (w >> (3 * tag)) & 7;
        out_tags[fb + t - 1] = (float)tag;
    }
}

// ---------------------------------------------------------------------------
extern "C" void kernel_launch(void* const* d_in, const int* in_sizes, int n_in,
                              void* d_out, int out_size, void* d_ws, size_t ws_size,
                              hipStream_t stream)
{
    const int*   sent    = (const int*)  d_in[0];
    const float* mask    = (const float*)d_in[1];
    const float* emb     = (const float*)d_in[2];
    const float* h0      = (const float*)d_in[3];
    const float* c0      = (const float*)d_in[4];
    const float* w_ih_l0 = (const float*)d_in[5];
    const float* w_hh_l0 = (const float*)d_in[6];
    const float* b_l0    = (const float*)d_in[7];
    const float* w_ih_l1 = (const float*)d_in[8];
    const float* w_hh_l1 = (const float*)d_in[9];
    const float* b_l1    = (const float*)d_in[10];
    const float* w_ih_l2 = (const float*)d_in[11];
    const float* w_hh_l2 = (const float*)d_in[12];
    const float* b_l2    = (const float*)d_in[13];
    const float* w_tag   = (const float*)d_in[14];
    const float* b_tag   = (const float*)d_in[15];
    const float* trans   = (const float*)d_in[16];

    float* out = (float*)d_out;
    char* ws = (char*)d_ws;

    // workspace layout (bytes)
    unsigned short* xg    = (unsigned short*)(ws);                  // 52,428,800
    unsigned short* xa16  = (unsigned short*)(ws + 52428800L);      // 16,777,216
    unsigned short* xb16  = (unsigned short*)(ws + 69206016L);      // 16,777,216
    unsigned short* AbR   = (unsigned short*)(ws + 85983232L);      // 41,943,040
    float*          feats = (float*)(ws + 127926272L);              //  2,097,152
    unsigned*       bptrw = (unsigned*)(ws + 130023424L);           //    262,144
    unsigned short* Wb0   = (unsigned short*)(ws + 130285568L);     //    286,720
    unsigned short* Wb1   = (unsigned short*)(ws + 130572288L);     //    114,688
    unsigned short* Wb2   = (unsigned short*)(ws + 130686976L);     //    114,688
    int*            btag  = (int*)(ws + 130801664L);                //        512

    dim3 gridG(Mrows / 128, 7);   // 128x64 tiles over [65536, 448]

    // fused weight conversion (one launch for all 3 layers)
    conv_w3<<<1008, 256, 0, stream>>>(w_ih_l0, w_ih_l1, w_ih_l2, Wb0, Wb1, Wb2);

    // layer 0 (embedding gather -> bf16)
    conv_a<true><<<(Mrows * 40 + 255) / 256, 256, 0, stream>>>(emb, sent, AbR, 300, 320, 40);
    gemm_mfma<<<gridG, 256, 0, stream>>>(AbR, Wb0, b_l0, xg, 320);
    lstm_scan<<<256, 256, 0, stream>>>(xg, w_hh_l0, h0 + 0 * Bb * Hh, c0 + 0 * Bb * Hh, xa16);

    // layer 1 (scan output already in bf16 [M,128] A-layout)
    gemm_mfma<<<gridG, 256, 0, stream>>>(xa16, Wb1, b_l1, xg, 128);
    lstm_scan<<<256, 256, 0, stream>>>(xg, w_hh_l1, h0 + 2 * Bb * Hh, c0 + 2 * Bb * Hh, xb16);

    // layer 2
    gemm_mfma<<<gridG, 256, 0, stream>>>(xb16, Wb2, b_l2, xg, 128);
    lstm_scan<<<256, 256, 0, stream>>>(xg, w_hh_l2, h0 + 4 * Bb * Hh, c0 + 4 * Bb * Hh, xa16);

    // tag projection + viterbi + backtrace
    feats_kernel<<<Mrows * 8 / 256, 256, 0, stream>>>(xa16, w_tag, b_tag, mask, feats);
    viterbi_fwd<<<Bb / 8, 64, 0, stream>>>(feats, trans, bptrw, out, btag);
    backtrack<<<1, 128, 0, stream>>>(bptrw, btag, out + Bb);
}

// Round 19
// 1115.304 us; speedup vs baseline: 1.2327x; 1.0685x over previous
//
#include <hip/hip_runtime.h>

#define NEGV (-10000.0f)

static constexpr int Bb    = 128;
static constexpr int Tt    = 512;
static constexpr int Mrows = Bb * Tt;   // 65536
static constexpr int Hh    = 50;
static constexpr int START = 5;

typedef __attribute__((ext_vector_type(8))) short bf16x8;
typedef __attribute__((ext_vector_type(4))) float f32x4;

__device__ __forceinline__ float fsig(float x) {
    return __builtin_amdgcn_rcpf(1.0f + __expf(-x));
}
__device__ __forceinline__ float ftanh(float x) {
    return 2.0f * __builtin_amdgcn_rcpf(1.0f + __expf(-2.0f * x)) - 1.0f;
}
__device__ __forceinline__ unsigned short f2bf(float f) {
    unsigned u = __float_as_uint(f);
    u = (u + 0x7fffu + ((u >> 16) & 1u)) >> 16;   // RNE
    return (unsigned short)u;
}
#define BF(u) __uint_as_float(((unsigned)(u)) << 16)

// ---------------------------------------------------------------------------
// Fused weight conversion for all three layers (one launch)
// ---------------------------------------------------------------------------
__global__ __launch_bounds__(256) void conv_w3(
    const float* __restrict__ s0, const float* __restrict__ s1,
    const float* __restrict__ s2,
    unsigned short* __restrict__ d0, unsigned short* __restrict__ d1,
    unsigned short* __restrict__ d2)
{
    int gid = blockIdx.x * 256 + threadIdx.x;
    const float* src; unsigned short* dst; int K, KP, off;
    if (gid < 143360)      { src = s0; dst = d0; K = 300; KP = 320; off = gid; }
    else if (gid < 200704) { src = s1; dst = d1; K = 100; KP = 128; off = gid - 143360; }
    else if (gid < 258048) { src = s2; dst = d2; K = 100; KP = 128; off = gid - 200704; }
    else return;
    int r = off / KP, c = off % KP;
    float v = (r < 400 && c < K) ? src[r * K + c] : 0.f;
    dst[off] = f2bf(v);
}

// ---------------------------------------------------------------------------
// Convert A rows (gathered, layer 0 only) fp32 -> [M][KP] bf16
// ---------------------------------------------------------------------------
template <bool GATHER>
__global__ __launch_bounds__(256) void conv_a(
    const float* __restrict__ src, const int* __restrict__ idx,
    unsigned short* __restrict__ dst, int K, int KP, int cpr)
{
    long gid = (long)blockIdx.x * 256 + threadIdx.x;
    long tot = (long)Mrows * cpr;
    if (gid >= tot) return;
    long m = gid / cpr;
    int p = (int)(gid - m * cpr) * 8;
    const float* s = src + (GATHER ? (long)idx[m] : m) * K;
    unsigned u0, u1, u2, u3;
    {
        float x0 = (p + 0 < K) ? s[p + 0] : 0.f;
        float x1 = (p + 1 < K) ? s[p + 1] : 0.f;
        float x2 = (p + 2 < K) ? s[p + 2] : 0.f;
        float x3 = (p + 3 < K) ? s[p + 3] : 0.f;
        float x4 = (p + 4 < K) ? s[p + 4] : 0.f;
        float x5 = (p + 5 < K) ? s[p + 5] : 0.f;
        float x6 = (p + 6 < K) ? s[p + 6] : 0.f;
        float x7 = (p + 7 < K) ? s[p + 7] : 0.f;
        u0 = (unsigned)f2bf(x0) | ((unsigned)f2bf(x1) << 16);
        u1 = (unsigned)f2bf(x2) | ((unsigned)f2bf(x3) << 16);
        u2 = (unsigned)f2bf(x4) | ((unsigned)f2bf(x5) << 16);
        u3 = (unsigned)f2bf(x6) | ((unsigned)f2bf(x7) << 16);
    }
    uint4 v = make_uint4(u0, u1, u2, u3);
    *(uint4*)(dst + m * KP + p) = v;
}

// ---------------------------------------------------------------------------
// bf16 MFMA GEMM: C[M,400]bf16 = A[M,KP]bf16 @ W[448,KP]bf16^T + bias
// (verified since r10)
// ---------------------------------------------------------------------------
__global__ __launch_bounds__(256) void gemm_mfma(
    const unsigned short* __restrict__ Ab,   // [M][KP]
    const unsigned short* __restrict__ Wb,   // [448][KP]
    const float* __restrict__ bias,          // [400]
    unsigned short* __restrict__ C,          // [M][400] bf16
    int KP)
{
    __shared__ unsigned short As[128][40];
    __shared__ unsigned short Ws[64][40];

    const int tid = threadIdx.x;
    const int m0 = blockIdx.x * 128;
    const int n0 = blockIdx.y * 64;

    const int w  = tid >> 6, l = tid & 63;
    const int wm = (w >> 1) * 64;
    const int wn = (w & 1) * 32;
    const int lr = l & 15;
    const int lk = (l >> 4) * 8;

    f32x4 acc[4][2] = {};

    for (int k0 = 0; k0 < KP; k0 += 32) {
        __syncthreads();
        {
            int c = tid;
            int r = c >> 2, p = (c & 3) * 8;
            *(bf16x8*)&As[r][p] = *(const bf16x8*)(Ab + (long)(m0 + r) * KP + k0 + p);
            c = tid + 256;
            r = c >> 2; p = (c & 3) * 8;
            *(bf16x8*)&As[r][p] = *(const bf16x8*)(Ab + (long)(m0 + r) * KP + k0 + p);
            r = tid >> 2; p = (tid & 3) * 8;
            *(bf16x8*)&Ws[r][p] = *(const bf16x8*)(Wb + (long)(n0 + r) * KP + k0 + p);
        }
        __syncthreads();

        bf16x8 af0 = *(const bf16x8*)&As[wm +  0 + lr][lk];
        bf16x8 af1 = *(const bf16x8*)&As[wm + 16 + lr][lk];
        bf16x8 af2 = *(const bf16x8*)&As[wm + 32 + lr][lk];
        bf16x8 af3 = *(const bf16x8*)&As[wm + 48 + lr][lk];
        bf16x8 wf0 = *(const bf16x8*)&Ws[wn +  0 + lr][lk];
        bf16x8 wf1 = *(const bf16x8*)&Ws[wn + 16 + lr][lk];

        acc[0][0] = __builtin_amdgcn_mfma_f32_16x16x32_bf16(af0, wf0, acc[0][0], 0, 0, 0);
        acc[0][1] = __builtin_amdgcn_mfma_f32_16x16x32_bf16(af0, wf1, acc[0][1], 0, 0, 0);
        acc[1][0] = __builtin_amdgcn_mfma_f32_16x16x32_bf16(af1, wf0, acc[1][0], 0, 0, 0);
        acc[1][1] = __builtin_amdgcn_mfma_f32_16x16x32_bf16(af1, wf1, acc[1][1], 0, 0, 0);
        acc[2][0] = __builtin_amdgcn_mfma_f32_16x16x32_bf16(af2, wf0, acc[2][0], 0, 0, 0);
        acc[2][1] = __builtin_amdgcn_mfma_f32_16x16x32_bf16(af2, wf1, acc[2][1], 0, 0, 0);
        acc[3][0] = __builtin_amdgcn_mfma_f32_16x16x32_bf16(af3, wf0, acc[3][0], 0, 0, 0);
        acc[3][1] = __builtin_amdgcn_mfma_f32_16x16x32_bf16(af3, wf1, acc[3][1], 0, 0, 0);
    }

    const int orow = (l >> 4) * 4;
    const int ocol = l & 15;
    #pragma unroll
    for (int a = 0; a < 4; ++a) {
        #pragma unroll
        for (int bb = 0; bb < 2; ++bb) {
            const int col = n0 + wn + bb * 16 + ocol;
            if (col < 400) {
                const float bv = bias[col];
                #pragma unroll
                for (int i = 0; i < 4; ++i) {
                    const long row = m0 + wm + a * 16 + orow + i;
                    C[row * 400 + col] = f2bf(acc[a][bb][i] + bv);
                }
            }
        }
    }
}

// ---------------------------------------------------------------------------
// LSTM scan: r15/r18 exact (verified 280us, absmax 2.0). At its structural
// latency floor (~1300cy/step across 9 tested topologies) — frozen.
// ---------------------------------------------------------------------------
#define H(J) __uint_as_float((unsigned)__builtin_amdgcn_readlane((int)__float_as_uint(hreg), (J)))

__global__ void
__attribute__((amdgpu_flat_work_group_size(256, 256), amdgpu_waves_per_eu(1, 1)))
lstm_scan(
    const unsigned short* __restrict__ xg,  // [M,400] bf16 (bias added)
    const float* __restrict__ w_hh,         // [2,200,50]
    const float* __restrict__ h0,           // layer base: [2,B,50]
    const float* __restrict__ c0,
    unsigned short* __restrict__ xout)      // [M,128] bf16, cols 100-127 = 0
{
    const int b    = blockIdx.x & 127;
    const int dir  = blockIdx.x >> 7;
    const int tid  = threadIdx.x;
    const int lane = tid & 63;
    const int wv   = tid >> 6;

    __shared__ float pre[2][200];

    const int gr = (tid < 200) ? tid : 199;

    const float* wr = w_hh + ((long)dir * 200 + gr) * 50;
    float w0  = wr[0],  w1  = wr[1],  w2  = wr[2],  w3  = wr[3],  w4  = wr[4];
    float w5  = wr[5],  w6  = wr[6],  w7  = wr[7],  w8  = wr[8],  w9  = wr[9];
    float w10 = wr[10], w11 = wr[11], w12 = wr[12], w13 = wr[13], w14 = wr[14];
    float w15 = wr[15], w16 = wr[16], w17 = wr[17], w18 = wr[18], w19 = wr[19];
    float w20 = wr[20], w21 = wr[21], w22 = wr[22], w23 = wr[23], w24 = wr[24];
    float w25 = wr[25], w26 = wr[26], w27 = wr[27], w28 = wr[28], w29 = wr[29];
    float w30 = wr[30], w31 = wr[31], w32 = wr[32], w33 = wr[33], w34 = wr[34];
    float w35 = wr[35], w36 = wr[36], w37 = wr[37], w38 = wr[38], w39 = wr[39];
    float w40 = wr[40], w41 = wr[41], w42 = wr[42], w43 = wr[43], w44 = wr[44];
    float w45 = wr[45], w46 = wr[46], w47 = wr[47], w48 = wr[48], w49 = wr[49];
    asm volatile("" : "+v"(w0), "+v"(w1), "+v"(w2), "+v"(w3), "+v"(w4),
                      "+v"(w5), "+v"(w6), "+v"(w7), "+v"(w8), "+v"(w9));
    asm volatile("" : "+v"(w10), "+v"(w11), "+v"(w12), "+v"(w13), "+v"(w14),
                      "+v"(w15), "+v"(w16), "+v"(w17), "+v"(w18), "+v"(w19));
    asm volatile("" : "+v"(w20), "+v"(w21), "+v"(w22), "+v"(w23), "+v"(w24),
                      "+v"(w25), "+v"(w26), "+v"(w27), "+v"(w28), "+v"(w29));
    asm volatile("" : "+v"(w30), "+v"(w31), "+v"(w32), "+v"(w33), "+v"(w34),
                      "+v"(w35), "+v"(w36), "+v"(w37), "+v"(w38), "+v"(w39));
    asm volatile("" : "+v"(w40), "+v"(w41), "+v"(w42), "+v"(w43), "+v"(w44),
                      "+v"(w45), "+v"(w46), "+v"(w47), "+v"(w48), "+v"(w49));

    float hreg = 0.f, c = 0.f;
    if (lane < 50) {
        c    = c0[((long)dir * Bb + b) * Hh + lane];
        hreg = h0[((long)dir * Bb + b) * Hh + lane];
    }
    __syncthreads();

    const long rowbase = (long)b * Tt;
    const unsigned short* xbase = xg + rowbase * 400 + dir * 200 + gr;
    const int ocol = (lane < 50) ? (dir * 50 + lane) : (100 + dir * 14 + (lane - 50));
    unsigned short* op = xout + rowbase * 128 + ocol;

    #define XLD(s)  xbase[(long)(dir ? (Tt - 1 - (s)) : (s)) * 400]
    #define TTOF(s) (dir ? (Tt - 1 - (s)) : (s))

    #define STEP(PRE, XIN, TT) do {                                         \
        if (tid < 200) {                                                    \
            float s0 = BF(XIN), s1 = 0.f, s2 = 0.f, s3 = 0.f;               \
            s0 += w0 *H(0);  s1 += w1 *H(1);  s2 += w2 *H(2);  s3 += w3 *H(3);  \
            s0 += w4 *H(4);  s1 += w5 *H(5);  s2 += w6 *H(6);  s3 += w7 *H(7);  \
            s0 += w8 *H(8);  s1 += w9 *H(9);  s2 += w10*H(10); s3 += w11*H(11); \
            s0 += w12*H(12); s1 += w13*H(13); s2 += w14*H(14); s3 += w15*H(15); \
            s0 += w16*H(16); s1 += w17*H(17); s2 += w18*H(18); s3 += w19*H(19); \
            s0 += w20*H(20); s1 += w21*H(21); s2 += w22*H(22); s3 += w23*H(23); \
            s0 += w24*H(24); s1 += w25*H(25); s2 += w26*H(26); s3 += w27*H(27); \
            s0 += w28*H(28); s1 += w29*H(29); s2 += w30*H(30); s3 += w31*H(31); \
            s0 += w32*H(32); s1 += w33*H(33); s2 += w34*H(34); s3 += w35*H(35); \
            s0 += w36*H(36); s1 += w37*H(37); s2 += w38*H(38); s3 += w39*H(39); \
            s0 += w40*H(40); s1 += w41*H(41); s2 += w42*H(42); s3 += w43*H(43); \
            s0 += w44*H(44); s1 += w45*H(45); s2 += w46*H(46); s3 += w47*H(47); \
            s0 += w48*H(48); s1 += w49*H(49);                               \
            (PRE)[tid] = (s0 + s1) + (s2 + s3);                             \
        }                                                                   \
        asm volatile("s_waitcnt lgkmcnt(0)\n\ts_barrier" ::: "memory");     \
        {                                                                   \
            unsigned short val = 0;                                        \
            if (lane < 50) {                                                \
                const float gi = fsig((PRE)[lane]);                         \
                const float gf = fsig((PRE)[50 + lane]);                    \
                const float gc = ftanh((PRE)[100 + lane]);                  \
                const float go = fsig((PRE)[150 + lane]);                   \
                c = gf * c + gi * gc;                                       \
                hreg = go * ftanh(c);                                       \
                val = f2bf(hreg);                                           \
            }                                                               \
            if (wv == 0) op[(long)(TT) * 128] = val;                        \
        }                                                                   \
    } while (0)

    unsigned xc0 = XLD(0), xc1 = XLD(1), xc2 = XLD(2), xc3 = XLD(3);
    unsigned xn0 = 0, xn1 = 0, xn2 = 0, xn3 = 0;

    for (int blk = 0; blk < Tt / 4; ++blk) {
        const int s0i = blk * 4;
        if (blk < Tt / 4 - 1) {
            xn0 = XLD(s0i + 4); xn1 = XLD(s0i + 5);
            xn2 = XLD(s0i + 6); xn3 = XLD(s0i + 7);
        }
        STEP(pre[0], xc0, TTOF(s0i + 0));
        STEP(pre[1], xc1, TTOF(s0i + 1));
        STEP(pre[0], xc2, TTOF(s0i + 2));
        STEP(pre[1], xc3, TTOF(s0i + 3));
        xc0 = xn0; xc1 = xn1; xc2 = xn2; xc3 = xn3;
    }
    #undef STEP
    #undef XLD
    #undef TTOF
}

// ---------------------------------------------------------------------------
// feats[row, i] = (x_bf16[row,:100] . w_tag[i,:] + b_tag[i]) * mask[row]
// ---------------------------------------------------------------------------
__global__ __launch_bounds__(256) void feats_kernel(
    const unsigned short* __restrict__ x, // [M,128] bf16
    const float* __restrict__ w_tag,      // [7,100]
    const float* __restrict__ b_tag,      // [7]
    const float* __restrict__ mask,       // [M]
    float* __restrict__ feats)            // [M,8]
{
    const int gid = blockIdx.x * 256 + threadIdx.x;
    const int row = gid >> 3;
    const int i   = gid & 7;
    if (row >= Mrows) return;
    if (i == 7) { feats[(long)row * 8 + 7] = 0.f; return; }
    const unsigned* xr = (const unsigned*)(x + (long)row * 128);
    const float* wr = w_tag + i * 100;
    float acc = b_tag[i];
    #pragma unroll
    for (int q = 0; q < 50; ++q) {
        unsigned v = xr[q];
        float2 w2 = *(const float2*)(wr + 2 * q);
        acc += __uint_as_float(v << 16) * w2.x
             + __uint_as_float(v & 0xffff0000u) * w2.y;
    }
    feats[(long)row * 8 + i] = acc * mask[row];
}

// ---------------------------------------------------------------------------
// Viterbi forward + FUSED backtrack. 8 lanes per batch row; 4-deep feats
// prefetch; 3-level first-index-wins tree argmax (halves the serial compare
// chain, preserves jnp.argmax first-tie semantics); after the forward pass
// each block backtracks its own 8 rows (same lane wrote the bptr words ->
// vmcnt(0) suffices; loads are tag-independent-addressed so they pipeline).
// ---------------------------------------------------------------------------
__global__ __launch_bounds__(64) void viterbi_fwd(
    const float* __restrict__ feats,   // [M,8]
    const float* __restrict__ trans,   // [7,7]
    unsigned int* __restrict__ bptrw,  // [T*B]
    float* __restrict__ best_score,    // [B] -> d_out
    float* __restrict__ out_tags)      // [B*T] -> d_out+128
{
    const int lane = threadIdx.x;
    const int sub  = lane >> 3;
    const int i    = lane & 7;
    const int b    = blockIdx.x * 8 + sub;
    const int base = lane & 56;

    float tr[7];
    #pragma unroll
    for (int j = 0; j < 7; ++j) tr[j] = (i < 7) ? trans[i * 7 + j] : -1e30f;

    float score = (i == START) ? 0.0f : NEGV;
    const long fb = (long)b * Tt;

    float ft0 = feats[(fb + 0) * 8 + i];
    float ft1 = feats[(fb + 1) * 8 + i];
    float ft2 = feats[(fb + 2) * 8 + i];
    float ft3 = feats[(fb + 3) * 8 + i];

    for (int t = 0; t < Tt; ++t) {
        const float ftn = (t + 4 < Tt) ? feats[(fb + t + 4) * 8 + i] : 0.f;
        const float m0 = __shfl(score, base | 0, 64) + tr[0];
        const float m1 = __shfl(score, base | 1, 64) + tr[1];
        const float m2 = __shfl(score, base | 2, 64) + tr[2];
        const float m3 = __shfl(score, base | 3, 64) + tr[3];
        const float m4 = __shfl(score, base | 4, 64) + tr[4];
        const float m5 = __shfl(score, base | 5, 64) + tr[5];
        const float m6 = __shfl(score, base | 6, 64) + tr[6];
        // first-index-wins tree argmax (replace only on strict >)
        float b0 = m0; int j0 = 0; if (m1 > b0) { b0 = m1; j0 = 1; }
        float b1 = m2; int j1 = 2; if (m3 > b1) { b1 = m3; j1 = 3; }
        float b2 = m4; int j2 = 4; if (m5 > b2) { b2 = m5; j2 = 5; }
        if (b1 > b0) { b0 = b1; j0 = j1; }
        if (m6 > b2) { b2 = m6; j2 = 6; }
        if (b2 > b0) { b0 = b2; j0 = j2; }
        if (i < 7) score = b0 + ft0;
        unsigned v = (i < 7) ? ((unsigned)j0 << (3 * i)) : 0u;
        v |= __shfl_xor(v, 1, 64);
        v |= __shfl_xor(v, 2, 64);
        v |= __shfl_xor(v, 4, 64);
        if (i == 0) bptrw[(long)t * Bb + b] = v;
        ft0 = ft1; ft1 = ft2; ft2 = ft3; ft3 = ftn;
    }

    float bestv = score;
    int bt = 0;
    #pragma unroll
    for (int j = 1; j < 7; ++j) {
        float sj = __shfl(score, base | j, 64);
        if (i == 0 && sj > bestv) { bestv = sj; bt = j; }
    }

    // drain our bptr stores, then backtrack this block's own rows
    asm volatile("s_waitcnt vmcnt(0)" ::: "memory");
    if (i == 0) {
        best_score[b] = bestv;
        int tag = bt;
        float* ot = out_tags + fb;
        ot[Tt - 1] = (float)tag;
        #pragma unroll 8
        for (int t = Tt - 1; t >= 1; --t) {
            unsigned w = bptrw[(long)t * Bb + b];
            tag = (w >> (3 * tag)) & 7;
            ot[t - 1] = (float)tag;
        }
    }
}

// ---------------------------------------------------------------------------
extern "C" void kernel_launch(void* const* d_in, const int* in_sizes, int n_in,
                              void* d_out, int out_size, void* d_ws, size_t ws_size,
                              hipStream_t stream)
{
    const int*   sent    = (const int*)  d_in[0];
    const float* mask    = (const float*)d_in[1];
    const float* emb     = (const float*)d_in[2];
    const float* h0      = (const float*)d_in[3];
    const float* c0      = (const float*)d_in[4];
    const float* w_ih_l0 = (const float*)d_in[5];
    const float* w_hh_l0 = (const float*)d_in[6];
    const float* b_l0    = (const float*)d_in[7];
    const float* w_ih_l1 = (const float*)d_in[8];
    const float* w_hh_l1 = (const float*)d_in[9];
    const float* b_l1    = (const float*)d_in[10];
    const float* w_ih_l2 = (const float*)d_in[11];
    const float* w_hh_l2 = (const float*)d_in[12];
    const float* b_l2    = (const float*)d_in[13];
    const float* w_tag   = (const float*)d_in[14];
    const float* b_tag   = (const float*)d_in[15];
    const float* trans   = (const float*)d_in[16];

    float* out = (float*)d_out;
    char* ws = (char*)d_ws;

    // workspace layout (bytes)
    unsigned short* xg    = (unsigned short*)(ws);                  // 52,428,800
    unsigned short* xa16  = (unsigned short*)(ws + 52428800L);      // 16,777,216
    unsigned short* xb16  = (unsigned short*)(ws + 69206016L);      // 16,777,216
    unsigned short* AbR   = (unsigned short*)(ws + 85983232L);      // 41,943,040
    float*          feats = (float*)(ws + 127926272L);              //  2,097,152
    unsigned*       bptrw = (unsigned*)(ws + 130023424L);           //    262,144
    unsigned short* Wb0   = (unsigned short*)(ws + 130285568L);     //    286,720
    unsigned short* Wb1   = (unsigned short*)(ws + 130572288L);     //    114,688
    unsigned short* Wb2   = (unsigned short*)(ws + 130686976L);     //    114,688

    dim3 gridG(Mrows / 128, 7);   // 128x64 tiles over [65536, 448]

    // fused weight conversion (one launch for all 3 layers)
    conv_w3<<<1008, 256, 0, stream>>>(w_ih_l0, w_ih_l1, w_ih_l2, Wb0, Wb1, Wb2);

    // layer 0 (embedding gather -> bf16)
    conv_a<true><<<(Mrows * 40 + 255) / 256, 256, 0, stream>>>(emb, sent, AbR, 300, 320, 40);
    gemm_mfma<<<gridG, 256, 0, stream>>>(AbR, Wb0, b_l0, xg, 320);
    lstm_scan<<<256, 256, 0, stream>>>(xg, w_hh_l0, h0 + 0 * Bb * Hh, c0 + 0 * Bb * Hh, xa16);

    // layer 1 (scan output already in bf16 [M,128] A-layout)
    gemm_mfma<<<gridG, 256, 0, stream>>>(xa16, Wb1, b_l1, xg, 128);
    lstm_scan<<<256, 256, 0, stream>>>(xg, w_hh_l1, h0 + 2 * Bb * Hh, c0 + 2 * Bb * Hh, xb16);

    // layer 2
    gemm_mfma<<<gridG, 256, 0, stream>>>(xb16, Wb2, b_l2, xg, 128);
    lstm_scan<<<256, 256, 0, stream>>>(xg, w_hh_l2, h0 + 4 * Bb * Hh, c0 + 4 * Bb * Hh, xa16);

    // tag projection + fused viterbi/backtrack
    feats_kernel<<<Mrows * 8 / 256, 256, 0, stream>>>(xa16, w_tag, b_tag, mask, feats);
    viterbi_fwd<<<Bb / 8, 64, 0, stream>>>(feats, trans, bptrw, out, out + Bb);
}